// Round 1
// baseline (206.556 us; speedup 1.0000x reference)
//
#include <hip/hip_runtime.h>
#include <cstddef>

#define B_ 8
#define CIN_ 64
#define COUT_ 64
#define N_ 16384
#define K_ 9
#define L_ 32768   // STRIDE * N_

// One-time (per launch) transpose of weight [O][C][K] -> [K][C][O] so the
// hot loop reads 32 contiguous lane-uniform floats per (k,c) -> s_load_dwordx.
__global__ void wt_transpose_kernel(const float* __restrict__ w, float* __restrict__ wt) {
    int i = blockIdx.x * 256 + threadIdx.x;
    if (i >= COUT_ * CIN_ * K_) return;
    int k = i % K_;
    int c = (i / K_) % CIN_;
    int o = i / (K_ * CIN_);
    wt[(k * CIN_ + c) * COUT_ + o] = w[i];
}

// Thread owns t = l/2; computes outputs l=2t (even taps k=0,2,4,6,8) and
// l=2t+1 (odd taps k=1,3,5,7) for a 32-wide slice of COUT. No parity
// divergence: every lane does all 288 FMAs per c with full exec mask.
template <bool TRANS>
__global__ __launch_bounds__(256) void wct_kernel(
    const float* __restrict__ x, const float* __restrict__ coords,
    const float* __restrict__ sigma_p, const float* __restrict__ w,
    float* __restrict__ out)
{
    const int t = blockIdx.x * 256 + threadIdx.x;   // t in [0, N)
    const int b = blockIdx.y;
    const int obase = blockIdx.z * 32;

    const float inv_sigma = 1.0f / sigma_p[0];

    // --- coords gate s[k] for both parities ---
    const float* cb = coords + (size_t)b * 3 * L_;
    float ctr[2][3];
#pragma unroll
    for (int d = 0; d < 3; ++d) {
        ctr[0][d] = cb[d * L_ + 2 * t];
        ctr[1][d] = cb[d * L_ + 2 * t + 1];
    }
    float s[9];
#pragma unroll
    for (int k = 0; k < 9; ++k) {
        const int par = k & 1;
        const int pos = 2 * t + par + k - 4;          // = l + k - 4, always even
        const bool valid = (pos >= 0) & (pos < L_);   // coords pad == x pad region
        const int pc = min(max(pos, 0), L_ - 1);
        const float d0 = cb[0 * L_ + pc] - ctr[par][0];
        const float d1 = cb[1 * L_ + pc] - ctr[par][1];
        const float d2 = cb[2 * L_ + pc] - ctr[par][2];
        const float sv = fmaxf(1.0f - sqrtf(d0 * d0 + d1 * d1 + d2 * d2) * inv_sigma, 0.0f);
        s[k] = valid ? sv : 0.0f;
    }

    // x sample indices m = t-2..t+2 (clamped; invalid taps have s[k]=0)
    int xi[5];
#pragma unroll
    for (int j = 0; j < 5; ++j) xi[j] = min(max(t - 2 + j, 0), N_ - 1);

    float acc[2][32];
#pragma unroll
    for (int p = 0; p < 2; ++p)
#pragma unroll
        for (int o = 0; o < 32; ++o) acc[p][o] = 0.0f;

    const float* xb = x + (size_t)b * CIN_ * N_;
    for (int c = 0; c < CIN_; ++c) {
        const float* xc = xb + c * N_;
        float xv[5];
#pragma unroll
        for (int j = 0; j < 5; ++j) xv[j] = xc[xi[j]];   // 5 coalesced dword loads
#pragma unroll
        for (int k = 0; k < 9; ++k) {
            // tap k reads x offset j = ceil(k/2) and accumulates into parity k&1
            const float xs = xv[(k + 1) >> 1] * s[k];
#pragma unroll
            for (int o = 0; o < 32; ++o) {
                float wv;
                if (TRANS) wv = w[(size_t)(k * CIN_ + c) * COUT_ + obase + o];      // uniform, contiguous -> s_load
                else       wv = w[((size_t)(obase + o) * CIN_ + c) * K_ + k];       // fallback, uniform strided
                acc[k & 1][o] = fmaf(wv, xs, acc[k & 1][o]);
            }
        }
    }

    // store both parities per o as one float2 (8B/lane, coalesced)
#pragma unroll
    for (int o = 0; o < 32; ++o) {
        float2 v = make_float2(acc[0][o], acc[1][o]);
        *reinterpret_cast<float2*>(out + (size_t)(b * COUT_ + obase + o) * L_ + 2 * t) = v;
    }
}

extern "C" void kernel_launch(void* const* d_in, const int* in_sizes, int n_in,
                              void* d_out, int out_size, void* d_ws, size_t ws_size,
                              hipStream_t stream) {
    const float* x      = (const float*)d_in[0];
    const float* coords = (const float*)d_in[1];
    const float* sigma  = (const float*)d_in[2];
    const float* w      = (const float*)d_in[3];
    float* out = (float*)d_out;

    const size_t wt_bytes = (size_t)COUT_ * CIN_ * K_ * sizeof(float);
    dim3 grid(N_ / 256, B_, 2);
    if (ws_size >= wt_bytes) {
        float* wt = (float*)d_ws;
        wt_transpose_kernel<<<dim3((COUT_ * CIN_ * K_ + 255) / 256), 256, 0, stream>>>(w, wt);
        wct_kernel<true><<<grid, dim3(256, 1, 1), 0, stream>>>(x, coords, sigma, wt, out);
    } else {
        wct_kernel<false><<<grid, dim3(256, 1, 1), 0, stream>>>(x, coords, sigma, w, out);
    }
}

// Round 2
// 131.660 us; speedup vs baseline: 1.5689x; 1.5689x over previous
//
#include <hip/hip_runtime.h>
#include <cstddef>
#include <cstdint>

#define B_ 8
#define CIN_ 64
#define COUT_ 64
#define N_ 16384
#define K_ 9
#define L_ 32768
#define TT 128

typedef __attribute__((ext_vector_type(8))) short  short8v;
typedef __attribute__((ext_vector_type(4))) float  float4v;
typedef __attribute__((ext_vector_type(4))) int    int4v;

static __device__ __forceinline__ uint16_t f2bf(float f) {
    uint32_t u = __float_as_uint(f);
    uint32_t r = (u + 0x7FFFu + ((u >> 16) & 1u)) >> 16;   // round-to-nearest-even
    return (uint16_t)r;
}

// ---------------- prep 1: x [b][c][m] f32  ->  xTg [b][m][c] bf16 (no swizzle) ----
__global__ __launch_bounds__(256) void xt_prep(const float* __restrict__ x,
                                               uint16_t* __restrict__ xTg) {
    __shared__ float tile[64][65];          // +1 pad breaks bank conflicts
    const int m0 = blockIdx.x * 64;
    const int b  = blockIdx.y;
    const float* xb = x + (size_t)b * CIN_ * N_;
    const int mloc = threadIdx.x & 63;
    const int cq   = threadIdx.x >> 6;      // 0..3
#pragma unroll
    for (int i = 0; i < 16; ++i) {
        int c = cq + i * 4;
        tile[c][mloc] = xb[(size_t)c * N_ + m0 + mloc];   // coalesced rows
    }
    __syncthreads();
    uint16_t* xtb = xTg + (size_t)b * N_ * CIN_;
    const int dw   = threadIdx.x & 31;      // dword within 64-c row
    const int mrow = threadIdx.x >> 5;      // 0..7
#pragma unroll
    for (int i = 0; i < 8; ++i) {
        int m = mrow + i * 8;
        uint32_t pk = (uint32_t)f2bf(tile[dw * 2][m]) |
                      ((uint32_t)f2bf(tile[dw * 2 + 1][m]) << 16);
        ((uint32_t*)(xtb + (size_t)(m0 + m) * CIN_))[dw] = pk;   // coalesced
    }
}

// ---------------- prep 2: weight [o][c][k] f32 -> Wprep frag-ordered bf16 --------
// frag f = (jg*2 + ks)*4 + wv ; lane holds A[row=o=wv*16+(l&15)][c = ks*32+(l>>4)*8+e]
__global__ void w_prep(const float* __restrict__ w, uint16_t* __restrict__ wp) {
    int i = blockIdx.x * 256 + threadIdx.x;
    if (i >= 72 * 64) return;
    int lane = i & 63, f = i >> 6;
    int wv = f & 3, ks = (f >> 2) & 1, jg = f >> 3;
    int p = jg >= 5 ? 1 : 0;
    int j = p ? jg - 5 : jg;
    int ktap = 2 * j + p;
    int o  = wv * 16 + (lane & 15);
    int cb = ks * 32 + (lane >> 4) * 8;
    uint16_t* dst = wp + (size_t)f * 512 + lane * 8;
#pragma unroll
    for (int e = 0; e < 8; ++e)
        dst[e] = f2bf(w[((size_t)o * CIN_ + cb + e) * K_ + ktap]);
}

// ---------------- main: per-tap GEMM (MFMA) + post-scale by coords gate ----------
__global__ __launch_bounds__(256, 2) void wct_mfma(
    const uint16_t* __restrict__ xTg, const float* __restrict__ coords,
    const float* __restrict__ sigma_p, const uint16_t* __restrict__ wp,
    float* __restrict__ out)
{
    __shared__ uint16_t xs[136 * 64];       // 17408 B, XOR-swizzled rows [m][c] bf16
    __shared__ float s_lds[9][128];         // gate values per (tap-group, t)

    const int t0   = blockIdx.x * TT;
    const int b    = blockIdx.y;
    const int tid  = threadIdx.x;
    const int lane = tid & 63;
    const int wv   = tid >> 6;              // wave id -> o-slice
    const int tcol = lane & 15;
    const int kgrp = lane >> 4;             // 0..3

    // ---- persistent W fragments: 18 per wave (9 jg x 2 ksteps) ----
    short8v wfrag[18];
#pragma unroll
    for (int jg = 0; jg < 9; ++jg)
#pragma unroll
        for (int ks = 0; ks < 2; ++ks) {
            int f = (jg * 2 + ks) * 4 + wv;
            wfrag[jg * 2 + ks] = *(const short8v*)(wp + (size_t)f * 512 + lane * 8);
        }

    // ---- stage x tile rows m0..m0+135 (m0 = t0-2), swizzled ds_write ----
    {
        const uint16_t* xtb = xTg + (size_t)b * N_ * CIN_;
        const int m0 = t0 - 2;
#pragma unroll
        for (int i = 0; i < 5; ++i) {
            int ci = tid + 256 * i;                  // 16B chunk id
            if (ci < 1088) {
                int r   = ci >> 3;                   // LDS row (128 B = 8 chunks)
                int off = (ci & 7) * 16;             // byte offset within row
                int gm  = m0 + r;
                gm = gm < 0 ? 0 : (gm > N_ - 1 ? N_ - 1 : gm);   // s-gate kills clamped rows
                int4v v = *(const int4v*)((const char*)(xtb + (size_t)gm * CIN_) + off);
                int key = ((m0 + r) & 7) << 4;       // same key recomputed on read
                *(int4v*)((char*)xs + r * 128 + (off ^ key)) = v;
            }
        }
    }

    // ---- compute coords gate s[jg][t] ----
    {
        const float* cb = coords + (size_t)b * 3 * L_;
        const float inv_sigma = 1.0f / sigma_p[0];
#pragma unroll
        for (int i = 0; i < 5; ++i) {
            int slot = tid + 256 * i;
            if (slot < 1152) {
                int jg = slot >> 7, tl = slot & 127;
                int p = jg >= 5 ? 1 : 0;
                int j = p ? jg - 5 : jg;
                int t = t0 + tl;
                int m = t + j - (p ? 1 : 2);
                int lout = 2 * t + p;
                bool valid = (m >= 0) & (m < N_);
                int pc = 2 * m;
                pc = pc < 0 ? 0 : (pc > L_ - 1 ? L_ - 1 : pc);
                float d0 = cb[pc] - cb[lout];
                float d1 = cb[L_ + pc] - cb[L_ + lout];
                float d2 = cb[2 * L_ + pc] - cb[2 * L_ + lout];
                float sv = fmaxf(1.0f - sqrtf(d0 * d0 + d1 * d1 + d2 * d2) * inv_sigma, 0.0f);
                s_lds[jg][tl] = valid ? sv : 0.0f;
            }
        }
    }
    __syncthreads();

    // ---- 9 tap-GEMMs, post-scaled into parity accumulators ----
    float4v accE[8], accO[8];
#pragma unroll
    for (int nf = 0; nf < 8; ++nf) { accE[nf] = (float4v){0,0,0,0}; accO[nf] = (float4v){0,0,0,0}; }

#pragma unroll
    for (int jg = 0; jg < 9; ++jg) {
        const int p    = jg >= 5 ? 1 : 0;
        const int j    = p ? jg - 5 : jg;
        const int joff = p ? j + 1 : j;                  // LDS row = tl + joff
        // swizzle key: (m & 7) with m = t0-2 + r, r = nf*16 + tcol + joff; nf*16 % 8 == 0
        const int key = ((tcol + joff - 2) & 7) << 4;
        const int row = tcol + joff;
        const char* bp0 = (const char*)xs + row * 128 + (((kgrp * 16) +   0 ^ key) );
        const char* bp1 = (const char*)xs + row * 128 + (((kgrp * 16) +  64) ^ key);

        float4v g[8];
#pragma unroll
        for (int nf = 0; nf < 8; ++nf) g[nf] = (float4v){0,0,0,0};
#pragma unroll
        for (int nf = 0; nf < 8; ++nf) {
            short8v bfrag = *(const short8v*)(bp0 + nf * 2048);
            g[nf] = __builtin_amdgcn_mfma_f32_16x16x32_bf16(wfrag[jg * 2 + 0], bfrag, g[nf], 0, 0, 0);
        }
#pragma unroll
        for (int nf = 0; nf < 8; ++nf) {
            short8v bfrag = *(const short8v*)(bp1 + nf * 2048);
            g[nf] = __builtin_amdgcn_mfma_f32_16x16x32_bf16(wfrag[jg * 2 + 1], bfrag, g[nf], 0, 0, 0);
        }
#pragma unroll
        for (int nf = 0; nf < 8; ++nf) {
            float sv = s_lds[jg][nf * 16 + tcol];
            if (p) {
                accO[nf][0] += sv * g[nf][0]; accO[nf][1] += sv * g[nf][1];
                accO[nf][2] += sv * g[nf][2]; accO[nf][3] += sv * g[nf][3];
            } else {
                accE[nf][0] += sv * g[nf][0]; accE[nf][1] += sv * g[nf][1];
                accE[nf][2] += sv * g[nf][2]; accE[nf][3] += sv * g[nf][3];
            }
        }
    }

    // ---- store: lane holds o = wv*16 + kgrp*4 + r (C/D row), t = t0+nf*16+tcol (col)
#pragma unroll
    for (int nf = 0; nf < 8; ++nf) {
        int t = t0 + nf * 16 + tcol;
#pragma unroll
        for (int r = 0; r < 4; ++r) {
            int o = wv * 16 + kgrp * 4 + r;
            float2 v = make_float2(accE[nf][r], accO[nf][r]);   // out[..][2t], out[..][2t+1]
            *(float2*)(out + ((size_t)(b * COUT_ + o)) * L_ + 2 * t) = v;
        }
    }
}

// ---------------- fallback (round-1 fp32 kernel) if ws is too small -------------
__global__ void wt_transpose_kernel(const float* __restrict__ w, float* __restrict__ wt) {
    int i = blockIdx.x * 256 + threadIdx.x;
    if (i >= COUT_ * CIN_ * K_) return;
    int k = i % K_, c = (i / K_) % CIN_, o = i / (K_ * CIN_);
    wt[(k * CIN_ + c) * COUT_ + o] = w[i];
}

__global__ __launch_bounds__(256) void wct_kernel(
    const float* __restrict__ x, const float* __restrict__ coords,
    const float* __restrict__ sigma_p, const float* __restrict__ w,
    float* __restrict__ out)
{
    const int t = blockIdx.x * 256 + threadIdx.x;
    const int b = blockIdx.y;
    const int obase = blockIdx.z * 32;
    const float inv_sigma = 1.0f / sigma_p[0];
    const float* cb = coords + (size_t)b * 3 * L_;
    float ctr[2][3];
#pragma unroll
    for (int d = 0; d < 3; ++d) { ctr[0][d] = cb[d * L_ + 2 * t]; ctr[1][d] = cb[d * L_ + 2 * t + 1]; }
    float s[9];
#pragma unroll
    for (int k = 0; k < 9; ++k) {
        const int par = k & 1;
        const int pos = 2 * t + par + k - 4;
        const bool valid = (pos >= 0) & (pos < L_);
        const int pc = min(max(pos, 0), L_ - 1);
        const float d0 = cb[0 * L_ + pc] - ctr[par][0];
        const float d1 = cb[1 * L_ + pc] - ctr[par][1];
        const float d2 = cb[2 * L_ + pc] - ctr[par][2];
        const float sv = fmaxf(1.0f - sqrtf(d0 * d0 + d1 * d1 + d2 * d2) * inv_sigma, 0.0f);
        s[k] = valid ? sv : 0.0f;
    }
    int xi[5];
#pragma unroll
    for (int j = 0; j < 5; ++j) xi[j] = min(max(t - 2 + j, 0), N_ - 1);
    float acc[2][32];
#pragma unroll
    for (int p = 0; p < 2; ++p)
#pragma unroll
        for (int o = 0; o < 32; ++o) acc[p][o] = 0.0f;
    const float* xb = x + (size_t)b * CIN_ * N_;
    for (int c = 0; c < CIN_; ++c) {
        const float* xc = xb + c * N_;
        float xv[5];
#pragma unroll
        for (int j = 0; j < 5; ++j) xv[j] = xc[xi[j]];
#pragma unroll
        for (int k = 0; k < 9; ++k) {
            const float xs_ = xv[(k + 1) >> 1] * s[k];
#pragma unroll
            for (int o = 0; o < 32; ++o)
                acc[k & 1][o] = fmaf(w[(size_t)(k * CIN_ + c) * COUT_ + obase + o], xs_, acc[k & 1][o]);
        }
    }
#pragma unroll
    for (int o = 0; o < 32; ++o)
        *reinterpret_cast<float2*>(out + (size_t)(b * COUT_ + obase + o) * L_ + 2 * t) =
            make_float2(acc[0][o], acc[1][o]);
}

extern "C" void kernel_launch(void* const* d_in, const int* in_sizes, int n_in,
                              void* d_out, int out_size, void* d_ws, size_t ws_size,
                              hipStream_t stream) {
    const float* x      = (const float*)d_in[0];
    const float* coords = (const float*)d_in[1];
    const float* sigma  = (const float*)d_in[2];
    const float* w      = (const float*)d_in[3];
    float* out = (float*)d_out;

    const size_t xt_bytes = (size_t)B_ * N_ * CIN_ * sizeof(uint16_t);   // 16 MB
    const size_t wp_bytes = (size_t)72 * 64 * 8 * sizeof(uint16_t);      // 72 KB

    if (ws_size >= xt_bytes + wp_bytes) {
        uint16_t* xTg = (uint16_t*)d_ws;
        uint16_t* wp  = (uint16_t*)((char*)d_ws + xt_bytes);
        xt_prep<<<dim3(N_ / 64, B_), 256, 0, stream>>>(x, xTg);
        w_prep<<<dim3(18), 256, 0, stream>>>(w, wp);
        wct_mfma<<<dim3(N_ / TT, B_), 256, 0, stream>>>(xTg, coords, sigma, wp, out);
    } else if (ws_size >= (size_t)COUT_ * CIN_ * K_ * sizeof(float)) {
        float* wt = (float*)d_ws;
        wt_transpose_kernel<<<dim3((COUT_ * CIN_ * K_ + 255) / 256), 256, 0, stream>>>(w, wt);
        wct_kernel<<<dim3(N_ / 256, B_, 2), 256, 0, stream>>>(x, coords, sigma, wt, out);
    }
}